// Round 9
// baseline (42758.743 us; speedup 1.0000x reference)
//
#include <hip/hip_runtime.h>
#include <stdint.h>

typedef unsigned short u16;

#define BB    16
#define TENC  256
#define TDEC  200
#define NMELS 80
#define EDIM  512
#define PREN  256
#define ARN   1024
#define ATTN  128
#define NFILT 32
#define KSIZE 31

// ---- ws layout (floats); total 7.36 MB (proven budget >= 7.44 MB) ----
#define OFF_AW     0
#define OFF_AWC    4096
#define OFF_AC     8192
#define OFF_DC     24576
#define OFF_CTX    40960
#define OFF_XCAT1  49152
#define OFF_XCAT2  77824
#define STATE_F    118784
#define OFF_PRETU  118784
#define OFF_PMU    528384
#define OFF_Z      790528

#define N_AWIH 3145728
#define N_AWHH 4194304
#define N_DWIH 6291456
#define N_DWHH 4194304

__host__ __device__ inline void tf2x32(uint32_t k0, uint32_t k1, uint32_t x0, uint32_t x1,
                                       uint32_t &y0, uint32_t &y1) {
  uint32_t ks2 = k0 ^ k1 ^ 0x1BD11BDAu;
  x0 += k0; x1 += k1;
  const int R0[4] = {13, 15, 26, 6};
  const int R1[4] = {17, 29, 16, 24};
#pragma unroll
  for (int g = 0; g < 5; ++g) {
    const int *R = (g & 1) ? R1 : R0;
#pragma unroll
    for (int i = 0; i < 4; ++i) {
      x0 += x1;
      x1 = (x1 << R[i]) | (x1 >> (32 - R[i]));
      x1 ^= x0;
    }
    switch (g) {
      case 0: x0 += k1;  x1 += ks2 + 1u; break;
      case 1: x0 += ks2; x1 += k0 + 2u;  break;
      case 2: x0 += k0;  x1 += k1 + 3u;  break;
      case 3: x0 += k1;  x1 += ks2 + 4u; break;
      case 4: x0 += ks2; x1 += k0 + 5u;  break;
    }
  }
  y0 = x0; y1 = x1;
}

__device__ inline bool keep_mask(uint32_t k0, uint32_t k1, uint32_t idx) {
  uint32_t y0, y1;
  tf2x32(k0, k1, 0u, idx, y0, y1);
  return (((y0 ^ y1) >> 31) == 0u);
}

__device__ inline float bf2f(u16 v) {
  union { uint32_t u; float f; } x;
  x.u = ((uint32_t)v) << 16;
  return x.f;
}
__device__ inline u16 f2bf(float f) {
  union { float f; uint32_t u; } x;
  x.f = f;
  uint32_t r = ((x.u >> 16) & 1u) + 0x7FFFu;
  return (u16)((x.u + r) >> 16);
}
__device__ inline float sigm(float x) { return 1.f / (1.f + __expf(-x)); }
__device__ inline float ftanh(float x) {
  x = fminf(fmaxf(x, -15.f), 15.f);
  float e = __expf(2.f * x);
  return (e - 1.f) / (e + 1.f);
}

__global__ __launch_bounds__(256) void k_wconv(const float *__restrict__ s,
                                               u16 *__restrict__ d, int n) {
  int i = (blockIdx.x * 256 + threadIdx.x) * 4;
  int stride = gridDim.x * 256 * 4;
  for (; i < n; i += stride) {
    float4 v = *(const float4 *)(s + i);
    ushort4 o;
    o.x = f2bf(v.x); o.y = f2bf(v.y); o.z = f2bf(v.z); o.w = f2bf(v.w);
    *(ushort4 *)(d + i) = o;
  }
}
__global__ __launch_bounds__(256) void k_copyf4(const float *__restrict__ s,
                                                float *__restrict__ d, int n4) {
  int i = blockIdx.x * 256 + threadIdx.x;
  int stride = gridDim.x * 256;
  for (; i < n4; i += stride)
    ((float4 *)d)[i] = ((const float4 *)s)[i];
}

__global__ __launch_bounds__(256) void k_prenet1(const float *__restrict__ dec_in,
                                                 const float *__restrict__ W1,
                                                 u16 *__restrict__ x1,
                                                 uint32_t k0, uint32_t k1) {
  int bid = blockIdx.x;
  int t = bid >> 4, b = bid & 15;
  int tid = threadIdx.x;
  __shared__ float di[NMELS];
  if (tid < NMELS)
    di[tid] = (t == 0) ? 0.f : dec_in[((size_t)b * NMELS + tid) * TDEC + (t - 1)];
  __syncthreads();
  int j = tid;
  float acc = 0.f;
#pragma unroll 4
  for (int m = 0; m < NMELS; ++m) acc += di[m] * W1[(size_t)m * PREN + j];
  acc = fmaxf(acc, 0.f);
  uint32_t idx = ((uint32_t)(t * BB + b)) * PREN + (uint32_t)j;
  acc = keep_mask(k0, k1, idx) ? acc * 2.f : 0.f;
  x1[(t * BB + b) * PREN + j] = f2bf(acc);
}

__global__ __launch_bounds__(256) void k_prenet2(const u16 *__restrict__ x1,
                                                 const float *__restrict__ W2,
                                                 u16 *__restrict__ preTu,
                                                 float *__restrict__ xpre0,
                                                 uint32_t k0, uint32_t k1) {
  int bid = blockIdx.x;
  int t = bid >> 4, b = bid & 15;
  int tid = threadIdx.x;
  __shared__ float xl[PREN];
  xl[tid] = bf2f(x1[(t * BB + b) * PREN + tid]);
  __syncthreads();
  int j = tid;
  float acc = 0.f;
#pragma unroll 4
  for (int k = 0; k < PREN; ++k) acc += xl[k] * W2[(size_t)k * PREN + j];
  acc = fmaxf(acc, 0.f);
  uint32_t idx = ((uint32_t)(t * BB + b)) * PREN + (uint32_t)j;
  acc = keep_mask(k0, k1, idx) ? acc * 2.f : 0.f;
  preTu[(size_t)t * 4096 + j * 16 + b] = f2bf(acc);
  if (t == 0) xpre0[j * 16 + b] = acc;
}

__global__ __launch_bounds__(256) void k_pm(const float *__restrict__ memory,
                                            const float *__restrict__ Wmem,
                                            u16 *__restrict__ pmu) {
  int p = blockIdx.x;
  int b = p & 15, jt = p >> 4;
  int tt = threadIdx.x;
  float acc[32];
#pragma unroll
  for (int j = 0; j < 32; ++j) acc[j] = 0.f;
  const float *mrow = memory + ((size_t)b * TENC + tt) * EDIM;
  const float *wb = Wmem + jt * 32;
  for (int e = 0; e < EDIM; ++e) {
    float mv = mrow[e];
    const float *wr = wb + (size_t)e * ATTN;
#pragma unroll
    for (int j = 0; j < 32; ++j) acc[j] += mv * wr[j];
  }
#pragma unroll
  for (int j = 0; j < 32; ++j)
    pmu[((size_t)(b * ATTN + jt * 32 + j)) * TENC + tt] = f2bf(acc[j]);
}

#define GBODY2(wx, wy, xr) { float4 x0 = xr[0], x1v = xr[1], x2 = xr[2], x3 = xr[3];      \
  a0[0]+=x0.x*wx;  a1[0]+=x0.x*wy;  a0[1]+=x0.y*wx;  a1[1]+=x0.y*wy;                      \
  a0[2]+=x0.z*wx;  a1[2]+=x0.z*wy;  a0[3]+=x0.w*wx;  a1[3]+=x0.w*wy;                      \
  a0[4]+=x1v.x*wx; a1[4]+=x1v.x*wy; a0[5]+=x1v.y*wx; a1[5]+=x1v.y*wy;                     \
  a0[6]+=x1v.z*wx; a1[6]+=x1v.z*wy; a0[7]+=x1v.w*wx; a1[7]+=x1v.w*wy;                     \
  a0[8]+=x2.x*wx;  a1[8]+=x2.x*wy;  a0[9]+=x2.y*wx;  a1[9]+=x2.y*wy;                      \
  a0[10]+=x2.z*wx; a1[10]+=x2.z*wy; a0[11]+=x2.w*wx; a1[11]+=x2.w*wy;                     \
  a0[12]+=x3.x*wx; a1[12]+=x3.x*wy; a0[13]+=x3.y*wx; a1[13]+=x3.y*wy;                     \
  a0[14]+=x3.z*wx; a1[14]+=x3.z*wy; a0[15]+=x3.w*wx; a1[15]+=x3.w*wy; }

template <int BK>
__global__ __launch_bounds__(256) void k_zgemmb(const u16 *__restrict__ Wih,
                                                const u16 *__restrict__ Whh,
                                                int lenIH,
                                                const float *__restrict__ xcat,
                                                float *__restrict__ z) {
  __shared__ float xs[BK * 16];
  int tid = threadIdx.x;
  int col = blockIdx.x * 512 + tid * 2;
  int kbase = blockIdx.y * BK;
  const float4 *xsrc = (const float4 *)(xcat + (size_t)kbase * 16);
#pragma unroll
  for (int i = 0; i < (BK * 4 + 255) / 256; ++i) {
    int idx = tid + i * 256;
    if (idx < BK * 4) ((float4 *)xs)[idx] = xsrc[idx];
  }
  __syncthreads();
  float a0[16], a1[16];
#pragma unroll
  for (int b = 0; b < 16; ++b) { a0[b] = 0.f; a1[b] = 0.f; }
  int n1 = lenIH - kbase;
  n1 = n1 < 0 ? 0 : (n1 > BK ? BK : n1);
  if (n1 == BK) {
    const u16 *wp = Wih + (size_t)kbase * 4096 + col;
#pragma unroll 4
    for (int kk = 0; kk < BK; ++kk) {
      uint32_t wv = *(const uint32_t *)(wp + (size_t)kk * 4096);
      float wx = bf2f((u16)wv), wy = bf2f((u16)(wv >> 16));
      const float4 *xr = (const float4 *)(xs + kk * 16);
      GBODY2(wx, wy, xr)
    }
  } else if (n1 == 0) {
    const u16 *wp = Whh + (size_t)(kbase - lenIH) * 4096 + col;
#pragma unroll 4
    for (int kk = 0; kk < BK; ++kk) {
      uint32_t wv = *(const uint32_t *)(wp + (size_t)kk * 4096);
      float wx = bf2f((u16)wv), wy = bf2f((u16)(wv >> 16));
      const float4 *xr = (const float4 *)(xs + kk * 16);
      GBODY2(wx, wy, xr)
    }
  } else {
    const u16 *wp = Wih + (size_t)kbase * 4096 + col;
    for (int kk = 0; kk < n1; ++kk) {
      uint32_t wv = *(const uint32_t *)(wp + (size_t)kk * 4096);
      float wx = bf2f((u16)wv), wy = bf2f((u16)(wv >> 16));
      const float4 *xr = (const float4 *)(xs + kk * 16);
      GBODY2(wx, wy, xr)
    }
    const u16 *wp2 = Whh + col;
    for (int kk = n1; kk < BK; ++kk) {
      uint32_t wv = *(const uint32_t *)(wp2 + (size_t)(kk - n1) * 4096);
      float wx = bf2f((u16)wv), wy = bf2f((u16)(wv >> 16));
      const float4 *xr = (const float4 *)(xs + kk * 16);
      GBODY2(wx, wy, xr)
    }
  }
  float *zo = z + ((size_t)blockIdx.y * 16) * 4096 + col;
#pragma unroll
  for (int b = 0; b < 16; ++b) {
    float2 v; v.x = a0[b]; v.y = a1[b];
    *(float2 *)(zo + (size_t)b * 4096) = v;
  }
}

__global__ __launch_bounds__(1024) void k_att(const float *__restrict__ z1p, int nch,
                                              const float *__restrict__ ab,
                                              float *__restrict__ ac,
                                              float *__restrict__ ahT1, float *__restrict__ ahT2,
                                              float *__restrict__ aw, float *__restrict__ awc,
                                              const u16 *__restrict__ pmu,
                                              const float *__restrict__ Wq,
                                              const float *__restrict__ vw,
                                              const float *__restrict__ convW,
                                              const float *__restrict__ ldW,
                                              const float *__restrict__ memory,
                                              const int *__restrict__ mlen,
                                              float *__restrict__ ctx,
                                              float *__restrict__ ctxT1, float *__restrict__ ctxT2,
                                              float *__restrict__ align_out, int t) {
  int b = blockIdx.x;
  int tid = threadIdx.x;
  __shared__ float ah_l[ARN];
  __shared__ float aw_l[288], awc_l[288];
  __shared__ float lc[TENC * 33];
  __shared__ float pqp[1024];
  __shared__ float pq[ATTN];
  __shared__ float ep[TENC * 4];
  __shared__ float e_l[TENC];
  __shared__ float cp[2][EDIM];
  __shared__ float red[32];
  __shared__ float s_max, s_inv;

  {
    int u = tid;
    float zi = 0.f, zf = 0.f, zg = 0.f, zo = 0.f;
    for (int kc = 0; kc < nch; ++kc) {
      const float *zb = z1p + ((size_t)(kc * 16 + b)) * 4096;
      zi += zb[u]; zf += zb[u + 1024]; zg += zb[u + 2048]; zo += zb[u + 3072];
    }
    zi += ab[u]; zf += ab[u + 1024]; zg += ab[u + 2048]; zo += ab[u + 3072];
    float cn = sigm(zf) * ac[b * 1024 + u] + sigm(zi) * ftanh(zg);
    float hn = sigm(zo) * ftanh(cn);
    ac[b * 1024 + u] = cn;
    ahT1[u * 16 + b] = hn;
    ahT2[u * 16 + b] = hn;
    ah_l[u] = hn;
  }
  if (tid < TENC) { aw_l[16 + tid] = aw[b * 256 + tid]; awc_l[16 + tid] = awc[b * 256 + tid]; }
  if (tid < 16) {
    aw_l[tid] = 0.f; aw_l[272 + tid] = 0.f;
    awc_l[tid] = 0.f; awc_l[272 + tid] = 0.f;
  }
  __syncthreads();

  {
    int j = tid & 127, kc = tid >> 7;
    float a = 0.f;
    const float *wq = Wq + (size_t)(kc * 128) * ATTN + j;
#pragma unroll 4
    for (int kk = 0; kk < 128; ++kk) a += ah_l[kc * 128 + kk] * wq[(size_t)kk * ATTN];
    pqp[j * 8 + kc] = a;
  }
  {
    int tt = tid & 255, fg = tid >> 8;
    float acc8[8] = {0, 0, 0, 0, 0, 0, 0, 0};
    for (int k = 0; k < KSIZE; ++k) {
      float a = aw_l[tt + k + 1];
      float c = awc_l[tt + k + 1];
#pragma unroll
      for (int f8 = 0; f8 < 8; ++f8) {
        int f = fg * 8 + f8;
        acc8[f8] += a * convW[f * 62 + k] + c * convW[f * 62 + 31 + k];
      }
    }
#pragma unroll
    for (int f8 = 0; f8 < 8; ++f8) lc[tt * 33 + fg * 8 + f8] = acc8[f8];
  }
  __syncthreads();
  if (tid < ATTN) {
    float s = 0.f;
#pragma unroll
    for (int kc = 0; kc < 8; ++kc) s += pqp[tid * 8 + kc];
    pq[tid] = s;
  }
  __syncthreads();
  {
    int tt = tid & 255, g = tid >> 8;
    float acc[32];
#pragma unroll
    for (int j = 0; j < 32; ++j) acc[j] = 0.f;
    for (int f = 0; f < NFILT; ++f) {
      float lv = lc[tt * 33 + f];
      const float *lw = ldW + f * ATTN + g * 32;
#pragma unroll
      for (int j = 0; j < 32; ++j) acc[j] += lv * lw[j];
    }
    const u16 *pmrow = pmu + ((size_t)(b * ATTN + g * 32)) * TENC + tt;
    const float *vwh = vw + g * 32;
    const float *pqh = pq + g * 32;
    float esum = 0.f;
#pragma unroll 4
    for (int j = 0; j < 32; ++j) {
      float s = acc[j] + pqh[j] + bf2f(pmrow[(size_t)j * TENC]);
      esum += ftanh(s) * vwh[j];
    }
    ep[tt * 4 + g] = esum;
  }
  __syncthreads();
  int len = mlen[b];
  if (tid < TENC) {
    float e = ep[tid * 4] + ep[tid * 4 + 1] + ep[tid * 4 + 2] + ep[tid * 4 + 3];
    if (tid >= len) e = -1e9f;
    e_l[tid] = e;
  }
  __syncthreads();
  if (tid < 32) {
    float m = -1e30f;
#pragma unroll
    for (int i = 0; i < 8; ++i) m = fmaxf(m, e_l[tid * 8 + i]);
    red[tid] = m;
  }
  __syncthreads();
  if (tid == 0) {
    float m = -1e30f;
    for (int i = 0; i < 32; ++i) m = fmaxf(m, red[i]);
    s_max = m;
  }
  __syncthreads();
  if (tid < TENC) e_l[tid] = __expf(e_l[tid] - s_max);
  __syncthreads();
  if (tid < 32) {
    float s = 0.f;
#pragma unroll
    for (int i = 0; i < 8; ++i) s += e_l[tid * 8 + i];
    red[tid] = s;
  }
  __syncthreads();
  if (tid == 0) {
    float s = 0.f;
    for (int i = 0; i < 32; ++i) s += red[i];
    s_inv = 1.f / s;
  }
  __syncthreads();
  if (tid < TENC) {
    float w = e_l[tid] * s_inv;
    e_l[tid] = w;
    aw[b * 256 + tid] = w;
    awc[b * 256 + tid] = awc_l[16 + tid] + w;
    align_out[((size_t)b * TDEC + t) * TENC + tid] = w;
  }
  __syncthreads();
  {
    int e = tid & 511, h = tid >> 9;
    int t0 = h * 128, t1 = min(len, (h + 1) * 128);
    float a = 0.f;
    for (int tt = t0; tt < t1; ++tt)
      a += e_l[tt] * memory[((size_t)b * TENC + tt) * EDIM + e];
    cp[h][e] = a;
  }
  __syncthreads();
  if (tid < EDIM) {
    float v = cp[0][tid] + cp[1][tid];
    ctx[b * EDIM + tid] = v;
    ctxT1[tid * 16 + b] = v;
    ctxT2[tid * 16 + b] = v;
  }
}

__global__ __launch_bounds__(512) void k_out(const float *__restrict__ z2p, int nch,
                                             const float *__restrict__ db,
                                             float *__restrict__ dc,
                                             float *__restrict__ dhT,
                                             const float *__restrict__ ctx,
                                             const float *__restrict__ projW,
                                             const float *__restrict__ projB,
                                             const float *__restrict__ gateW,
                                             const float *__restrict__ gateB,
                                             const u16 *__restrict__ preTu,
                                             float *__restrict__ xpre,
                                             float *__restrict__ mel_out,
                                             float *__restrict__ gate_out, int t) {
  int p = blockIdx.x;
  int tid = threadIdx.x;
  if (p >= 16) {
    if (t + 1 < TDEC) {
      int idx = (p - 16) * 512 + tid;
      xpre[idx] = bf2f(preTu[(size_t)(t + 1) * 4096 + idx]);
    }
    return;
  }
  int b = p;
  __shared__ float xl[1536];
  __shared__ float part[6 * 81];
#pragma unroll
  for (int r = 0; r < 2; ++r) {
    int u = r * 512 + tid;
    float zi = 0.f, zf = 0.f, zg = 0.f, zo = 0.f;
    for (int kc = 0; kc < nch; ++kc) {
      const float *zb = z2p + ((size_t)(kc * 16 + b)) * 4096;
      zi += zb[u]; zf += zb[u + 1024]; zg += zb[u + 2048]; zo += zb[u + 3072];
    }
    zi += db[u]; zf += db[u + 1024]; zg += db[u + 2048]; zo += db[u + 3072];
    float cn = sigm(zf) * dc[b * 1024 + u] + sigm(zi) * ftanh(zg);
    float hn = sigm(zo) * ftanh(cn);
    dc[b * 1024 + u] = cn;
    dhT[u * 16 + b] = hn;
    xl[u] = hn;
  }
  xl[1024 + tid] = ctx[b * 512 + tid];
  __syncthreads();
  {
    float a = 0.f;
    if (tid < 480) {
      int col = tid % 80, kc = tid / 80;
      const float *wp = projW + (size_t)(kc * 256) * 80 + col;
      const float *xk = xl + kc * 256;
#pragma unroll 4
      for (int kk = 0; kk < 256; ++kk) a += xk[kk] * wp[(size_t)kk * 80];
      part[kc * 81 + col] = a;
    } else if (tid < 486) {
      int kc = tid - 480;
      const float *xk = xl + kc * 256;
      const float *gk = gateW + kc * 256;
#pragma unroll 4
      for (int kk = 0; kk < 256; ++kk) a += xk[kk] * gk[kk];
      part[kc * 81 + 80] = a;
    }
  }
  __syncthreads();
  if (tid < 81) {
    float s = 0.f;
#pragma unroll
    for (int kc = 0; kc < 6; ++kc) s += part[kc * 81 + tid];
    if (tid < 80) {
      s += projB[tid];
      mel_out[((size_t)b * 80 + tid) * TDEC + t] = s;
    } else {
      s += gateB[0];
      gate_out[(size_t)b * TDEC + t] = s;
    }
  }
}

extern "C" void kernel_launch(void *const *d_in, const int *in_sizes, int n_in,
                              void *d_out, int out_size, void *d_ws, size_t ws_size,
                              hipStream_t stream) {
  (void)in_sizes; (void)n_in; (void)out_size; (void)ws_size;
  const float *memory = (const float *)d_in[0];
  const float *dec_in = (const float *)d_in[1];
  const int   *mlen   = (const int *)d_in[2];
  const float *pw1    = (const float *)d_in[3];
  const float *pw2    = (const float *)d_in[4];
  float *aWih   = (float *)d_in[5];
  float *aWhh   = (float *)d_in[6];
  const float *ab     = (const float *)d_in[7];
  const float *wq     = (const float *)d_in[8];
  const float *wmem   = (const float *)d_in[9];
  const float *vw     = (const float *)d_in[10];
  const float *convW  = (const float *)d_in[11];
  const float *ldW    = (const float *)d_in[12];
  float *dWih   = (float *)d_in[13];
  float *dWhh   = (float *)d_in[14];
  const float *db     = (const float *)d_in[15];
  const float *projW  = (const float *)d_in[16];
  const float *projB  = (const float *)d_in[17];
  const float *gateW  = (const float *)d_in[18];
  const float *gateB  = (const float *)d_in[19];

  float *out_mel  = (float *)d_out;
  float *out_gate = out_mel + (size_t)16 * 80 * 200;
  float *out_algn = out_gate + (size_t)16 * 200;

  float *ws = (float *)d_ws;
  float *aw    = ws + OFF_AW;
  float *awc   = ws + OFF_AWC;
  float *ac    = ws + OFF_AC;
  float *dc    = ws + OFF_DC;
  float *ctx   = ws + OFF_CTX;
  float *xcat1 = ws + OFF_XCAT1;
  float *xcat2 = ws + OFF_XCAT2;
  float *xpre  = xcat1;
  float *ctxT1 = xcat1 + 4096;
  float *ahT1  = xcat1 + 12288;
  float *ahT2  = xcat2;
  float *ctxT2 = xcat2 + 16384;
  float *dhT   = xcat2 + 24576;
  u16 *preTu = (u16 *)(ws + OFF_PRETU);
  u16 *pmu   = (u16 *)(ws + OFF_PMU);
  float *z   = ws + OFF_Z;
  u16 *x1u   = (u16 *)z;
  float *cvs = ws + OFF_PRETU;   // 6.88 MB conversion scratch (dead before prenet)

  hipMemsetAsync(ws, 0, STATE_F * sizeof(float), stream);

  // in-place bf16 conversion; every write lands only on already-dead f32 ranges
  u16 *dWihB = (u16 *)dWih;
  u16 *dWhhB = (u16 *)dWih + N_DWIH;
  u16 *aWihB = (u16 *)dWhh;
  u16 *aWhhB = (u16 *)dWhh + N_AWIH;
  k_wconv<<<512, 256, 0, stream>>>(dWih, (u16 *)cvs, N_DWIH / 2);
  k_wconv<<<512, 256, 0, stream>>>(dWih + N_DWIH / 2, dWihB + N_DWIH / 2, N_DWIH / 2);
  k_copyf4<<<512, 256, 0, stream>>>(cvs, dWih, 393216);   // N_DWIH/2 u16 = 393216 float4
  k_wconv<<<512, 256, 0, stream>>>(dWhh, dWhhB, N_DWHH);
  k_wconv<<<512, 256, 0, stream>>>(aWih, aWihB, N_AWIH);
  k_wconv<<<512, 256, 0, stream>>>(aWhh, aWhhB, N_AWHH);

  uint32_t K1a, K1b, K2a, K2b;
  tf2x32(0u, 42u, 0u, 0u, K1a, K1b);
  tf2x32(0u, 42u, 0u, 1u, K2a, K2b);

  k_prenet1<<<TDEC * BB, 256, 0, stream>>>(dec_in, pw1, x1u, K1a, K1b);
  k_prenet2<<<TDEC * BB, 256, 0, stream>>>(x1u, pw2, preTu, xpre, K2a, K2b);
  k_pm<<<64, 256, 0, stream>>>(memory, wmem, pmu);

  for (int t = 0; t < TDEC; ++t) {
    k_zgemmb<128><<<dim3(8, 14), 256, 0, stream>>>(aWihB, aWhhB, 768, xcat1, z);
    k_att<<<16, 1024, 0, stream>>>(z, 14, ab, ac, ahT1, ahT2, aw, awc, pmu,
                                   wq, vw, convW, ldW, memory, mlen,
                                   ctx, ctxT1, ctxT2, out_algn, t);
    k_zgemmb<160><<<dim3(8, 16), 256, 0, stream>>>(dWihB, dWhhB, 1536, xcat2, z);
    k_out<<<24, 512, 0, stream>>>(z, 16, db, dc, dhT, ctx, projW, projB,
                                  gateW, gateB, preTu, xpre,
                                  out_mel, out_gate, t);
  }
}